// Round 4
// baseline (743.688 us; speedup 1.0000x reference)
//
#include <hip/hip_runtime.h>
#include <stdint.h>

// Problem dims
#define NB  256
#define NT  100
#define NIN 128
#define NH  1024
#define NOUT 35

// d_out float offsets
#define O_SPK2 26214400ull
#define O_SPK3 52428800ull
#define O_SPK4 78643200ull
#define O_MEM4 79539200ull

// d_ws byte offsets (layout kept; WS_XT region now unused)
#define WS_XT   0ull
#define WS_Q1T  13107200ull   // 128*1024*4  = 524288
#define WS_K2T  13631488ull   // 1048576
#define WS_K3T  14680064ull   // 1048576
#define WS_K4T  15728640ull   // 1024*48 = 49152 (padded stride 48)

// scale = (w_max - w_min)/15 computed in python fp64 then cast to fp32
#define S2C ((float)((1.0 - 0.001) / 15.0))
#define S1C ((float)(1.0 / 15.0))

// ------------------------------------------------------------------
// K1 (v2): quantize weights. w2/w3 via LDS-tiled transpose (coalesced
// reads and writes). k4T + q1T per-element (tiny). xt deleted (k_spk1
// reads x directly now).
// grid: [0,512) w2/w3 tiles, then k4T, then q1T
// ------------------------------------------------------------------
__global__ __launch_bounds__(256) void k_prep(const float* __restrict__ w1,
                       const float* __restrict__ w2, const float* __restrict__ w3,
                       const float* __restrict__ w4, uint8_t* __restrict__ ws)
{
  const int bid = blockIdx.x, tid = threadIdx.x;
  if (bid < 512) {                          // 64x64 tile transpose-quantize
    const float* W = (bid < 256) ? w2 : w3;
    uint8_t* K = ws + ((bid < 256) ? WS_K2T : WS_K3T);
    const int tb = bid & 255;
    const int i0 = (tb & 15) << 6, j0 = (tb >> 4) << 6;
    __shared__ uint8_t tile[64 * 68];       // [i_local][j_local], stride 68
    const int jl = tid >> 4, iq = (tid & 15) << 2;
    #pragma unroll
    for (int k = 0; k < 4; ++k) {
      const int jloc = jl + k * 16;
      const float4 v = *(const float4*)&W[(size_t)(j0 + jloc) * 1024 + i0 + iq];
      float wc;
      wc = fminf(fmaxf(v.x, 0.001f), 1.0f); tile[(iq + 0) * 68 + jloc] = (uint8_t)(int)rintf((wc - 0.001f) / S2C);
      wc = fminf(fmaxf(v.y, 0.001f), 1.0f); tile[(iq + 1) * 68 + jloc] = (uint8_t)(int)rintf((wc - 0.001f) / S2C);
      wc = fminf(fmaxf(v.z, 0.001f), 1.0f); tile[(iq + 2) * 68 + jloc] = (uint8_t)(int)rintf((wc - 0.001f) / S2C);
      wc = fminf(fmaxf(v.w, 0.001f), 1.0f); tile[(iq + 3) * 68 + jloc] = (uint8_t)(int)rintf((wc - 0.001f) / S2C);
    }
    __syncthreads();
    const int li = tid >> 2, cq = tid & 3;
    const uint32_t* tp = (const uint32_t*)&tile[li * 68 + (cq << 4)];
    *(uint4*)&K[(size_t)(i0 + li) * 1024 + j0 + (cq << 4)] =
        make_uint4(tp[0], tp[1], tp[2], tp[3]);
    return;
  }
  long long id = (long long)(bid - 512) * 256 + tid;
  if (id < 49152) {                         // k4T stride 48, pad j>=35 with 0
    int i = (int)(id / 48), j = (int)(id % 48);
    uint8_t v = 0;
    if (j < NOUT) {
      float wv = w4[(size_t)j * 1024 + i];
      float wc = fminf(fmaxf(wv, 0.001f), 1.0f);
      v = (uint8_t)(int)rintf((wc - 0.001f) / S2C);
    }
    ws[WS_K4T + id] = v;
    return;
  }
  id -= 49152;
  if (id < 131072) {                        // q1T[i*1024+j] = fake_quant(w1[j][i]) fp32
    int i = (int)(id >> 10), j = (int)(id & 1023);
    float wv = w1[(size_t)j * 128 + i];
    float wc = fminf(fmaxf(wv, -0.5f), 0.5f);
    float q = rintf((wc + 0.5f) / S1C) * S1C - 0.5f;
    ((float*)(ws + WS_Q1T))[id] = q;
  }
}

// ------------------------------------------------------------------
// K2 (v3): fused layer-1 GEMM + LIF scan, x broadcast via v_readlane
// (SGPR operand into v_fmac) -- zero LDS traffic. 512 threads, each
// handles neurons tid and tid+512. FMA chain ascending-i per (t,j),
// bitwise identical to prior passing versions.
// ------------------------------------------------------------------
__global__ __launch_bounds__(512, 1) void k_spk1(const float* __restrict__ x,
                                                 const float* __restrict__ q1T,
                                                 float* __restrict__ out)
{
  const int b = blockIdx.x;
  const int tid = threadIdx.x;              // 0..511
  const int lane = tid & 63;
  const float* xb = x + (size_t)b * NT * NIN;
  float m1a = 0.f, m1b = 0.f;

  for (int c = 0; c < 4; ++c) {
    // x rows for this 25-t chunk into registers (each wave holds a copy)
    float xv0[25], xv1[25];
    #pragma unroll
    for (int tt = 0; tt < 25; ++tt) {
      const float* xr = xb + (size_t)(c * 25 + tt) * NIN;
      xv0[tt] = xr[lane] / 15.0f;
      xv1[tt] = xr[lane + 64] / 15.0f;
    }
    float acc0[25], acc1[25];
    #pragma unroll
    for (int tt = 0; tt < 25; ++tt) { acc0[tt] = 0.f; acc1[tt] = 0.f; }

    #pragma unroll 2
    for (int ib = 0; ib < 8; ++ib) {        // i = 0..63 via xv0
      float q0[8], q1v[8];
      #pragma unroll
      for (int u = 0; u < 8; ++u) {
        q0[u]  = q1T[(size_t)(ib * 8 + u) * NH + tid];
        q1v[u] = q1T[(size_t)(ib * 8 + u) * NH + tid + 512];
      }
      #pragma unroll
      for (int tt = 0; tt < 25; ++tt) {
        #pragma unroll
        for (int u = 0; u < 8; ++u) {
          float xs = __int_as_float(__builtin_amdgcn_readlane(__float_as_int(xv0[tt]), ib * 8 + u));
          acc0[tt] = fmaf(xs, q0[u], acc0[tt]);
          acc1[tt] = fmaf(xs, q1v[u], acc1[tt]);
        }
      }
    }
    #pragma unroll 2
    for (int ib = 8; ib < 16; ++ib) {       // i = 64..127 via xv1
      float q0[8], q1v[8];
      #pragma unroll
      for (int u = 0; u < 8; ++u) {
        q0[u]  = q1T[(size_t)(ib * 8 + u) * NH + tid];
        q1v[u] = q1T[(size_t)(ib * 8 + u) * NH + tid + 512];
      }
      #pragma unroll
      for (int tt = 0; tt < 25; ++tt) {
        #pragma unroll
        for (int u = 0; u < 8; ++u) {
          float xs = __int_as_float(__builtin_amdgcn_readlane(__float_as_int(xv1[tt]), ib * 8 + u - 64));
          acc0[tt] = fmaf(xs, q0[u], acc0[tt]);
          acc1[tt] = fmaf(xs, q1v[u], acc1[tt]);
        }
      }
    }
    // sequential LIF scan (subtract-reset), identical math/order
    #pragma unroll
    for (int tt = 0; tt < 25; ++tt) {
      const int t = c * 25 + tt;
      const size_t row = ((size_t)t * NB + b) * (size_t)NH;
      float rst0 = m1a > 1.0f ? 1.0f : 0.0f;
      m1a = fmaf(0.9f, m1a, acc0[tt]) - rst0;
      out[row + tid] = ((m1a - 1.0f) > 0.0f) ? 1.0f : 0.0f;
      float rst1 = m1b > 1.0f ? 1.0f : 0.0f;
      m1b = fmaf(0.9f, m1b, acc1[tt]) - rst1;
      out[row + tid + 512] = ((m1b - 1.0f) > 0.0f) ? 1.0f : 0.0f;
    }
  }
}

// ------------------------------------------------------------------
// K3 (v3): persistent per-batch-element SNN loop, 1024 threads.
// depth-4 gather pipelining, atomic-free list build (prefix over
// wcnt), packed-u16 gsum, rowsums fused as one-time full gathers.
// ------------------------------------------------------------------
#define ACC(V) do { \
  aE0 += (V).x & 0x00FF00FFu; aO0 += ((V).x >> 8) & 0x00FF00FFu; \
  aE1 += (V).y & 0x00FF00FFu; aO1 += ((V).y >> 8) & 0x00FF00FFu; \
  aE2 += (V).z & 0x00FF00FFu; aO2 += ((V).z >> 8) & 0x00FF00FFu; \
  aE3 += (V).w & 0x00FF00FFu; aO3 += ((V).w >> 8) & 0x00FF00FFu; } while (0)

__global__ __launch_bounds__(1024, 1) void k_main(
    const uint8_t* __restrict__ k2T, const uint8_t* __restrict__ k3T,
    const uint8_t* __restrict__ k4T, float* __restrict__ out)
{
  const int b = blockIdx.x;
  const int tid = threadIdx.x;
  const int lane = tid & 63;
  const int wave = tid >> 6;                // 16 gather groups

  __shared__ uint16_t list[1024];
  __shared__ uint4    pEa4[1024];           // [g][lane*4..+3] packed u16 (neurons 0,2 of quad)
  __shared__ uint4    pOa4[1024];           // neurons 1,3
  __shared__ uint4    wcnt4[4];
  uint32_t* pEa  = (uint32_t*)pEa4;
  uint32_t* pOa  = (uint32_t*)pOa4;
  uint32_t* wcnt = (uint32_t*)wcnt4;

  float m2 = 0.f, m3 = 0.f, m4 = 0.f;
  uint32_t nT, nL; bool cm;

  auto buildList = [&](uint64_t bal) {      // after barrier A (wcnt populated)
    const uint4 c0 = wcnt4[0], c1 = wcnt4[1], c2 = wcnt4[2], c3 = wcnt4[3];
    nT = c0.x + c0.y + c0.z + c0.w + c1.x + c1.y + c1.z + c1.w +
         c2.x + c2.y + c2.z + c2.w + c3.x + c3.y + c3.z + c3.w;
    cm = nT > 512;
    nL = cm ? (1024u - nT) : nT;
    uint32_t pre = 0;
    const int w = wave;
    pre += (w > 0)  ? c0.x : 0u;  pre += (w > 1)  ? c0.y : 0u;
    pre += (w > 2)  ? c0.z : 0u;  pre += (w > 3)  ? c0.w : 0u;
    pre += (w > 4)  ? c1.x : 0u;  pre += (w > 5)  ? c1.y : 0u;
    pre += (w > 6)  ? c1.z : 0u;  pre += (w > 7)  ? c1.w : 0u;
    pre += (w > 8)  ? c2.x : 0u;  pre += (w > 9)  ? c2.y : 0u;
    pre += (w > 10) ? c2.z : 0u;  pre += (w > 11) ? c2.w : 0u;
    pre += (w > 12) ? c3.x : 0u;  pre += (w > 13) ? c3.y : 0u;
    pre += (w > 14) ? c3.z : 0u;
    const uint32_t bs = cm ? ((uint32_t)(w << 6) - pre) : pre;
    const uint64_t cw = cm ? ~bal : bal;
    if ((cw >> lane) & 1ull)
      list[bs + (uint32_t)__popcll(cw & ((1ull << lane) - 1ull))] = (uint16_t)tid;
  };

  auto gatherBig = [&](const uint8_t* __restrict__ mat, uint32_t nLv) {
    uint32_t aE0=0,aE1=0,aE2=0,aE3=0,aO0=0,aO1=0,aO2=0,aO3=0;
    const uint8_t* bp = mat + (lane << 4);  // 64 lanes x 16B = full 1KB row
    uint32_t a = (uint32_t)wave;
    for (; a + 48 < nLv; a += 64) {         // 4 loads in flight
      uint32_t i0 = (uint32_t)__builtin_amdgcn_readfirstlane((int)list[a]);
      uint32_t i1 = (uint32_t)__builtin_amdgcn_readfirstlane((int)list[a + 16]);
      uint32_t i2 = (uint32_t)__builtin_amdgcn_readfirstlane((int)list[a + 32]);
      uint32_t i3 = (uint32_t)__builtin_amdgcn_readfirstlane((int)list[a + 48]);
      const uint4 v0 = *(const uint4*)(bp + ((size_t)i0 << 10));
      const uint4 v1 = *(const uint4*)(bp + ((size_t)i1 << 10));
      const uint4 v2 = *(const uint4*)(bp + ((size_t)i2 << 10));
      const uint4 v3 = *(const uint4*)(bp + ((size_t)i3 << 10));
      ACC(v0); ACC(v1); ACC(v2); ACC(v3);
    }
    for (; a < nLv; a += 16) {
      uint32_t i0 = (uint32_t)__builtin_amdgcn_readfirstlane((int)list[a]);
      const uint4 v0 = *(const uint4*)(bp + ((size_t)i0 << 10));
      ACC(v0);
    }
    const int basei = (wave << 8) + (lane << 2);
    *(uint4*)&pEa[basei] = make_uint4(aE0, aE1, aE2, aE3);
    *(uint4*)&pOa[basei] = make_uint4(aO0, aO1, aO2, aO3);
  };

  auto gatherAll = [&](const uint8_t* __restrict__ mat) {   // all 1024 rows
    uint32_t aE0=0,aE1=0,aE2=0,aE3=0,aO0=0,aO1=0,aO2=0,aO3=0;
    const uint8_t* bp = mat + (lane << 4);
    for (uint32_t a = (uint32_t)wave; a + 48 < 1024u; a += 64) {
      const uint4 v0 = *(const uint4*)(bp + ((size_t)a << 10));
      const uint4 v1 = *(const uint4*)(bp + ((size_t)(a + 16) << 10));
      const uint4 v2 = *(const uint4*)(bp + ((size_t)(a + 32) << 10));
      const uint4 v3 = *(const uint4*)(bp + ((size_t)(a + 48) << 10));
      ACC(v0); ACC(v1); ACC(v2); ACC(v3);
    }
    const int basei = (wave << 8) + (lane << 2);
    *(uint4*)&pEa[basei] = make_uint4(aE0, aE1, aE2, aE3);
    *(uint4*)&pOa[basei] = make_uint4(aO0, aO1, aO2, aO3);
  };

  auto gather4 = [&](uint32_t nLv) {        // k4T, 48-B rows, lanes 0..2
    uint32_t aE0=0,aE1=0,aE2=0,aE3=0,aO0=0,aO1=0,aO2=0,aO3=0;
    const uint8_t* bp = k4T + (lane << 4);
    uint32_t a = (uint32_t)wave;
    for (; a + 48 < nLv; a += 64) {
      uint32_t i0 = (uint32_t)__builtin_amdgcn_readfirstlane((int)list[a]);
      uint32_t i1 = (uint32_t)__builtin_amdgcn_readfirstlane((int)list[a + 16]);
      uint32_t i2 = (uint32_t)__builtin_amdgcn_readfirstlane((int)list[a + 32]);
      uint32_t i3 = (uint32_t)__builtin_amdgcn_readfirstlane((int)list[a + 48]);
      const uint4 v0 = *(const uint4*)(bp + (size_t)i0 * 48u);
      const uint4 v1 = *(const uint4*)(bp + (size_t)i1 * 48u);
      const uint4 v2 = *(const uint4*)(bp + (size_t)i2 * 48u);
      const uint4 v3 = *(const uint4*)(bp + (size_t)i3 * 48u);
      ACC(v0); ACC(v1); ACC(v2); ACC(v3);
    }
    for (; a < nLv; a += 16) {
      uint32_t i0 = (uint32_t)__builtin_amdgcn_readfirstlane((int)list[a]);
      const uint4 v0 = *(const uint4*)(bp + (size_t)i0 * 48u);
      ACC(v0);
    }
    const int basei = (wave << 8) + (lane << 2);
    *(uint4*)&pEa[basei] = make_uint4(aE0, aE1, aE2, aE3);
    *(uint4*)&pOa[basei] = make_uint4(aO0, aO1, aO2, aO3);
  };

  auto gather4All = [&]() {
    uint32_t aE0=0,aE1=0,aE2=0,aE3=0,aO0=0,aO1=0,aO2=0,aO3=0;
    const uint8_t* bp = k4T + (lane << 4);
    for (uint32_t a = (uint32_t)wave; a + 48 < 1024u; a += 64) {
      const uint4 v0 = *(const uint4*)(bp + (size_t)a * 48u);
      const uint4 v1 = *(const uint4*)(bp + (size_t)(a + 16) * 48u);
      const uint4 v2 = *(const uint4*)(bp + (size_t)(a + 32) * 48u);
      const uint4 v3 = *(const uint4*)(bp + (size_t)(a + 48) * 48u);
      ACC(v0); ACC(v1); ACC(v2); ACC(v3);
    }
    const int basei = (wave << 8) + (lane << 2);
    *(uint4*)&pEa[basei] = make_uint4(aE0, aE1, aE2, aE3);
    *(uint4*)&pOa[basei] = make_uint4(aO0, aO1, aO2, aO3);
  };

  // packed-u16 sum over 16 groups (fields can't carry: max 15360 < 2^16)
  auto gsum = [&](int jn) -> uint32_t {
    const int w = jn >> 2, sh = (jn & 2) << 3;
    const uint32_t* P = (jn & 1) ? pOa : pEa;
    uint32_t s = 0;
    #pragma unroll
    for (int g = 0; g < 16; ++g) s += P[(g << 8) + w];
    return (s >> sh) & 0xffffu;
  };

  // ---- fused rowsums (replaces k_rowsum) ----
  gatherAll(k2T);
  __syncthreads();
  const uint32_t r2v = gsum(tid);
  __syncthreads();
  gatherAll(k3T);
  __syncthreads();
  const uint32_t r3v = gsum(tid);
  __syncthreads();
  if (lane < 3) gather4All();
  __syncthreads();
  const uint32_t r4v = (tid < NOUT) ? gsum(tid) : 0u;

  float s1v = out[(size_t)b * NH + tid];    // prefetch spk1 row for t=0

  for (int t = 0; t < NT; ++t) {
    const size_t rowH = ((size_t)t * NB + b) * (size_t)NH;
    const size_t rowO = ((size_t)t * NB + b) * (size_t)NOUT;

    // ---- layer-1 spikes (precomputed by k_spk1); prefetch next row ----
    bool sA = s1v > 0.5f;
    {
      int tn = (t + 1 < NT) ? (t + 1) : t;
      s1v = out[((size_t)tn * NB + b) * (size_t)NH + tid];
    }
    uint64_t b1 = __ballot(sA);
    if (lane == 0) wcnt[wave] = (uint32_t)__popcll(b1);
    __syncthreads();                                         // A
    buildList(b1);
    __syncthreads();                                         // B
    const uint32_t n1 = nT, nl1 = nL; const bool cm1 = cm;
    if (nl1) gatherBig(k2T, nl1);
    __syncthreads();                                         // C

    // ---- layer 2 ----
    bool sp;
    {
      uint32_t gsv = nl1 ? gsum(tid) : 0u;
      uint32_t K = cm1 ? (r2v - gsv) : gsv;
      float cur = fmaf(S2C, (float)K, 0.001f * (float)n1);
      float rst = m2 > 1.0f ? 1.0f : 0.0f;
      m2 = fmaf(0.85f, m2, cur) - rst;
      sp = (m2 - 1.0f) > 0.0f;
      out[O_SPK2 + rowH + tid] = sp ? 1.0f : 0.0f;
    }
    uint64_t b2 = __ballot(sp);
    if (lane == 0) wcnt[wave] = (uint32_t)__popcll(b2);
    __syncthreads();                                         // D
    buildList(b2);
    __syncthreads();                                         // E
    const uint32_t n2 = nT, nl2 = nL; const bool cm2 = cm;
    if (nl2) gatherBig(k3T, nl2);
    __syncthreads();                                         // F

    // ---- layer 3 ----
    {
      uint32_t gsv = nl2 ? gsum(tid) : 0u;
      uint32_t K = cm2 ? (r3v - gsv) : gsv;
      float cur = fmaf(S2C, (float)K, 0.001f * (float)n2);
      float rst = m3 > 1.0f ? 1.0f : 0.0f;
      m3 = fmaf(0.8f, m3, cur) - rst;
      sp = (m3 - 1.0f) > 0.0f;
      out[O_SPK3 + rowH + tid] = sp ? 1.0f : 0.0f;
    }
    uint64_t b3 = __ballot(sp);
    if (lane == 0) wcnt[wave] = (uint32_t)__popcll(b3);
    __syncthreads();                                         // G
    buildList(b3);
    __syncthreads();                                         // H
    const uint32_t n3 = nT, nl3 = nL; const bool cm3 = cm;

    // ---- layer 4 gather (48-B padded rows; lanes 0..2 of each group) ----
    if (nl3 && lane < 3) gather4(nl3);
    __syncthreads();                                         // I

    // ---- layer 4 membrane (reset-to-zero) ----
    if (tid < NOUT) {
      uint32_t gsv = nl3 ? gsum(tid) : 0u;
      uint32_t K = cm3 ? (r4v - gsv) : gsv;
      float cur = fmaf(S2C, (float)K, 0.001f * (float)n3);
      float rst = m4 > 1.0f ? 1.0f : 0.0f;
      float bsv = fmaf(0.95f, m4, cur);
      m4 = (rst > 0.0f) ? 0.0f : bsv;
      out[O_SPK4 + rowO + tid] = ((m4 - 1.0f) > 0.0f) ? 1.0f : 0.0f;
      out[O_MEM4 + rowO + tid] = m4;
    }
  }
}
#undef ACC

extern "C" void kernel_launch(void* const* d_in, const int* in_sizes, int n_in,
                              void* d_out, int out_size, void* d_ws, size_t ws_size,
                              hipStream_t stream)
{
  const float* x  = (const float*)d_in[0];
  const float* w1 = (const float*)d_in[1];
  const float* w2 = (const float*)d_in[2];
  const float* w3 = (const float*)d_in[3];
  const float* w4 = (const float*)d_in[4];
  float* out = (float*)d_out;
  uint8_t* ws = (uint8_t*)d_ws;
  hipLaunchKernelGGL(k_prep, dim3(1216), dim3(256), 0, stream, w1, w2, w3, w4, ws);
  hipLaunchKernelGGL(k_spk1, dim3(256),  dim3(512), 0, stream,
                     x, (const float*)(ws + WS_Q1T), out);
  hipLaunchKernelGGL(k_main, dim3(256),  dim3(1024), 0, stream,
                     ws + WS_K2T, ws + WS_K3T, ws + WS_K4T, out);
}